// Round 4
// baseline (167.552 us; speedup 1.0000x reference)
//
#include <hip/hip_runtime.h>
#include <hip/hip_bf16.h>

#define SEQ   1024
#define NH    8
#define DH    64

typedef __attribute__((ext_vector_type(8))) _Float16 half8;
typedef __attribute__((ext_vector_type(4))) _Float16 half4;
typedef __attribute__((ext_vector_type(4))) float    f32x4;

#if __has_builtin(__builtin_amdgcn_exp2f)
#define EXP2F __builtin_amdgcn_exp2f
#else
#define EXP2F exp2f
#endif

__device__ inline unsigned pk2(float a, float b) {
  return __builtin_bit_cast(unsigned, __builtin_amdgcn_cvt_pkrtz(a, b));
}
__device__ inline void swap32(unsigned &a, unsigned &b) {
  asm("v_permlane32_swap_b32 %0, %1" : "+v"(a), "+v"(b));
}
__device__ inline void swap16(unsigned &a, unsigned &b) {
  asm("v_permlane16_swap_b32 %0, %1" : "+v"(a), "+v"(b));
}
__device__ inline half8 mk8(unsigned a, unsigned b, unsigned c, unsigned d) {
  union { unsigned u[4]; half8 h; } x;
  x.u[0] = a; x.u[1] = b; x.u[2] = c; x.u[3] = d;
  return x.h;
}

// ---------------- merged prep: cast x, weights, bias concat, dist->bin LUT ----------------
__global__ void prep_all(const float* __restrict__ x,
                         const float* __restrict__ qw, const float* __restrict__ kw,
                         const float* __restrict__ vw, const float* __restrict__ ow,
                         const float* __restrict__ qb, const float* __restrict__ kb,
                         const float* __restrict__ vb, const float* __restrict__ edges,
                         _Float16* __restrict__ xh, _Float16* __restrict__ wqkvh,
                         _Float16* __restrict__ owh, float* __restrict__ qkvbias,
                         unsigned char* __restrict__ lutd) {
  const int blk = blockIdx.x, tid = threadIdx.x;
  if (blk < 4096) {
    int g = blk * 256 + tid;
    float4 v = reinterpret_cast<const float4*>(x)[g];
    half4 u;
    u[0] = (_Float16)v.x; u[1] = (_Float16)v.y; u[2] = (_Float16)v.z; u[3] = (_Float16)v.w;
    reinterpret_cast<half4*>(xh)[g] = u;
  } else if (blk < 5122) {
    int g = (blk - 4096) * 256 + tid;
    if (g < 196608) {
      const float* src = (g < 65536) ? qw : (g < 131072) ? kw : vw;
      int lg = g & 65535;
      float4 v = reinterpret_cast<const float4*>(src)[lg];
      half4 u;
      u[0] = (_Float16)v.x; u[1] = (_Float16)v.y; u[2] = (_Float16)v.z; u[3] = (_Float16)v.w;
      reinterpret_cast<half4*>(wqkvh)[g] = u;
    } else if (g < 262144) {
      int lg = g - 196608;
      float4 v = reinterpret_cast<const float4*>(ow)[lg];
      half4 u;
      u[0] = (_Float16)v.x; u[1] = (_Float16)v.y; u[2] = (_Float16)v.z; u[3] = (_Float16)v.w;
      reinterpret_cast<half4*>(owh)[lg] = u;
    } else if (g < 262528) {
      int lg = g - 262144;
      const float* src = (lg < 128) ? qb : (lg < 256) ? kb : vb;
      int ll = lg & 127;
      reinterpret_cast<float4*>(qkvbias)[lg] = reinterpret_cast<const float4*>(src)[ll];
    }
  } else {
    int d = (blk - 5122) * 256 + tid;   // 0..5119
    float fd = (float)d;
    int bin = 0;
#pragma unroll
    for (int t = 0; t < 31; ++t) bin += (edges[t] < fd) ? 1 : 0;
    lutd[d] = (unsigned char)bin;
  }
}

// ---------------- prep: ebins[b][r][c] = bin | (p_c>p_r)<<5 | (mask_c==0)<<6 ----------------
__global__ __launch_bounds__(256) void prep_ebins(const int* __restrict__ positions,
                                                  const float* __restrict__ mask,
                                                  const unsigned char* __restrict__ lutd,
                                                  unsigned char* __restrict__ ebins) {
  __shared__ unsigned char lutl[5120];
  __shared__ int posl[SEQ];
  __shared__ unsigned char mk[SEQ];
  const int b = blockIdx.x >> 8, j0 = (blockIdx.x & 255) * 4;
  const int tid = threadIdx.x;
  for (int i = tid; i < 1280; i += 256)
    reinterpret_cast<unsigned*>(lutl)[i] = reinterpret_cast<const unsigned*>(lutd)[i];
  for (int i = tid; i < SEQ; i += 256) {
    posl[i] = positions[b * SEQ + i];
    mk[i] = (mask[b * SEQ + i] == 0.f) ? 64 : 0;
  }
  __syncthreads();
  const int c0 = tid * 4;
#pragma unroll
  for (int jj = 0; jj < 4; ++jj) {
    const int j = j0 + jj;
    const int pr = posl[j];
    unsigned out = 0;
#pragma unroll
    for (int r = 0; r < 4; ++r) {
      int c = c0 + r;
      int pc = posl[c];
      int d = pc - pr; d = d < 0 ? -d : d;
      if (d > 5119) d = 5119;
      unsigned e = lutl[d] | ((pc > pr) ? 32u : 0u) | (unsigned)mk[c];
      out |= e << (8 * r);
    }
    reinterpret_cast<unsigned*>(&ebins[(size_t)(b * SEQ + j) * SEQ])[tid] = out;
  }
}

// ---------------- QKV projection GEMM (128x128 tile, BK=64) ----------------
// Q -> [b][h][n][d] * 0.125 ; K -> [b][h][n][d] * log2(e) ; V -> transposed [b][h][d][n]
__global__ __launch_bounds__(256) void qkv_gemm2(const _Float16* __restrict__ xh,
                                                 const _Float16* __restrict__ wh,
                                                 const float* __restrict__ bias,
                                                 _Float16* __restrict__ qkv) {
  __shared__ __attribute__((aligned(16))) _Float16 As[128 * 72];
  __shared__ __attribute__((aligned(16))) _Float16 Bs[128 * 72];
  const int m0 = blockIdx.x * 128, n0 = blockIdx.y * 128;
  const int tid = threadIdx.x, w = tid >> 6, lane = tid & 63;
  const int lr = lane & 15, lg = lane >> 4;
  const int wr = (w >> 1) * 64, wc = (w & 1) * 64;
  f32x4 acc[4][4] = {};
  const int srow = tid >> 1, sseg = (tid & 1) * 32;
  for (int k0 = 0; k0 < 512; k0 += 64) {
#pragma unroll
    for (int s = 0; s < 4; ++s) {
      *reinterpret_cast<uint4*>(&As[srow * 72 + sseg + s * 8]) =
          *reinterpret_cast<const uint4*>(&xh[(m0 + srow) * 512 + k0 + sseg + s * 8]);
      *reinterpret_cast<uint4*>(&Bs[srow * 72 + sseg + s * 8]) =
          *reinterpret_cast<const uint4*>(&wh[(n0 + srow) * 512 + k0 + sseg + s * 8]);
    }
    __syncthreads();
#pragma unroll
    for (int kk = 0; kk < 2; ++kk) {
      half8 af[4], bf[4];
#pragma unroll
      for (int mt = 0; mt < 4; ++mt)
        af[mt] = *reinterpret_cast<const half8*>(&As[(wr + mt * 16 + lr) * 72 + kk * 32 + lg * 8]);
#pragma unroll
      for (int nt = 0; nt < 4; ++nt)
        bf[nt] = *reinterpret_cast<const half8*>(&Bs[(wc + nt * 16 + lr) * 72 + kk * 32 + lg * 8]);
#pragma unroll
      for (int mt = 0; mt < 4; ++mt)
#pragma unroll
        for (int nt = 0; nt < 4; ++nt)
          acc[mt][nt] = __builtin_amdgcn_mfma_f32_16x16x32_f16(af[mt], bf[nt], acc[mt][nt], 0, 0, 0);
    }
    __syncthreads();
  }
  const int p = n0 >> 9;   // block-uniform: 0=Q,1=K,2=V
  const float scl = (p == 0) ? 0.125f : (p == 1) ? 1.44269504f : 1.0f;
  if (p < 2) {
#pragma unroll
    for (int nt = 0; nt < 4; ++nt) {
      int n = n0 + wc + nt * 16 + lr;
      float bv = bias[n];
      int c = n & 511, h = c >> 6, d = c & 63;
#pragma unroll
      for (int mt = 0; mt < 4; ++mt)
#pragma unroll
        for (int r = 0; r < 4; ++r) {
          int m = m0 + wr + mt * 16 + lg * 4 + r;
          int bb = m >> 10, nn = m & 1023;
          qkv[p * 4194304 + ((bb * NH + h) * SEQ + nn) * DH + d] = (_Float16)((acc[mt][nt][r] + bv) * scl);
        }
    }
  } else {
#pragma unroll
    for (int nt = 0; nt < 4; ++nt) {
      int n = n0 + wc + nt * 16 + lr;
      float bv = bias[n];
      int c = n & 511, h = c >> 6, d = c & 63;
#pragma unroll
      for (int mt = 0; mt < 4; ++mt) {
        int m = m0 + wr + mt * 16 + lg * 4;
        int bb = m >> 10, nn = m & 1023;
        half4 st;
#pragma unroll
        for (int r = 0; r < 4; ++r) st[r] = (_Float16)(acc[mt][nt][r] + bv);
        *reinterpret_cast<half4*>(&qkv[8388608 + ((bb * NH + h) * DH + d) * SEQ + nn]) = st;
      }
    }
  }
}

// ---------------- fused attention: L2-direct fragments, 1 wave/block, no barriers ----------------
#define LOADKE(kf, ew, t) do {                                                              \
    const int kv0_ = (t) * 64;                                                              \
    _Pragma("unroll") for (int ct = 0; ct < 4; ++ct) {                                      \
      kf[ct * 2 + 0] = *reinterpret_cast<const half8*>(&Kg[(kv0_ + ct * 16 + lr) * DH + lg * 8]);      \
      kf[ct * 2 + 1] = *reinterpret_cast<const half8*>(&Kg[(kv0_ + ct * 16 + lr) * DH + 32 + lg * 8]); \
    }                                                                                       \
    _Pragma("unroll") for (int ct = 0; ct < 4; ++ct)                                        \
      _Pragma("unroll") for (int qc = 0; qc < 2; ++qc)                                      \
        ew[ct * 2 + qc] = *reinterpret_cast<const unsigned*>(                               \
            &ebins[(size_t)(b * SEQ + q_base + qc * 16 + lr) * SEQ + kv0_ + ct * 16 + lg * 4]); \
  } while (0)

#define COMPUTE(kf, ew, t) do {                                                             \
    const int kv0_ = (t) * 64;                                                              \
    half8 vf[8];                                                                            \
    _Pragma("unroll") for (int dt = 0; dt < 4; ++dt) {                                      \
      vf[dt * 2 + 0] = *reinterpret_cast<const half8*>(&Vtg[(dt * 16 + lr) * SEQ + kv0_ + lg * 8]);      \
      vf[dt * 2 + 1] = *reinterpret_cast<const half8*>(&Vtg[(dt * 16 + lr) * SEQ + kv0_ + 32 + lg * 8]); \
    }                                                                                       \
    f32x4 s[4][2];                                                                          \
    _Pragma("unroll") for (int ct = 0; ct < 4; ++ct)                                        \
      _Pragma("unroll") for (int qc = 0; qc < 2; ++qc) {                                    \
        unsigned e_ = ew[ct * 2 + qc];                                                      \
        s[ct][qc][0] = elutl[e_ & 127u];                                                    \
        s[ct][qc][1] = elutl[(e_ >> 8) & 127u];                                             \
        s[ct][qc][2] = elutl[(e_ >> 16) & 127u];                                            \
        s[ct][qc][3] = elutl[(e_ >> 24) & 127u];                                            \
      }                                                                                     \
    __builtin_amdgcn_s_setprio(1);                                                          \
    _Pragma("unroll") for (int ct = 0; ct < 4; ++ct)                                        \
      _Pragma("unroll") for (int qc = 0; qc < 2; ++qc) {                                    \
        s[ct][qc] = __builtin_amdgcn_mfma_f32_16x16x32_f16(kf[ct * 2 + 0], qf[qc][0], s[ct][qc], 0, 0, 0); \
        s[ct][qc] = __builtin_amdgcn_mfma_f32_16x16x32_f16(kf[ct * 2 + 1], qf[qc][1], s[ct][qc], 0, 0, 0); \
      }                                                                                     \
    __builtin_amdgcn_s_setprio(0);                                                          \
    unsigned W[2][4][2];                                                                    \
    _Pragma("unroll") for (int qc = 0; qc < 2; ++qc) {                                      \
      float a0 = fmaxf(fmaxf(s[0][qc][0], s[0][qc][1]), fmaxf(s[0][qc][2], s[0][qc][3]));   \
      float a1 = fmaxf(fmaxf(s[1][qc][0], s[1][qc][1]), fmaxf(s[1][qc][2], s[1][qc][3]));   \
      float a2 = fmaxf(fmaxf(s[2][qc][0], s[2][qc][1]), fmaxf(s[2][qc][2], s[2][qc][3]));   \
      float a3 = fmaxf(fmaxf(s[3][qc][0], s[3][qc][1]), fmaxf(s[3][qc][2], s[3][qc][3]));   \
      float pm = fmaxf(fmaxf(a0, a1), fmaxf(a2, a3));                                       \
      pm = fmaxf(pm, __shfl_xor(pm, 16));                                                   \
      pm = fmaxf(pm, __shfl_xor(pm, 32));                                                   \
      if (__any((int)(pm > m_run[qc] + 8.0f))) {                                            \
        float newm = fmaxf(m_run[qc], pm);                                                  \
        float alpha = EXP2F(m_run[qc] - newm);                                              \
        m_run[qc] = newm; l_run[qc] *= alpha;                                               \
        _Pragma("unroll") for (int dt = 0; dt < 4; ++dt) o[dt][qc] *= alpha;                \
      }                                                                                     \
      float ss_ = 0.f;                                                                      \
      _Pragma("unroll") for (int ct = 0; ct < 4; ++ct)                                      \
        _Pragma("unroll") for (int r = 0; r < 4; ++r) {                                     \
          float pv = EXP2F(s[ct][qc][r] - m_run[qc]);                                       \
          s[ct][qc][r] = pv; ss_ += pv;                                                     \
        }                                                                                   \
      l_run[qc] += ss_;                                                                     \
      _Pragma("unroll") for (int ct = 0; ct < 4; ++ct) {                                    \
        W[qc][ct][0] = pk2(s[ct][qc][0], s[ct][qc][1]);                                     \
        W[qc][ct][1] = pk2(s[ct][qc][2], s[ct][qc][3]);                                     \
      }                                                                                     \
      swap32(W[qc][0][0], W[qc][1][0]); swap32(W[qc][0][1], W[qc][1][1]);                   \
      swap32(W[qc][2][0], W[qc][3][0]); swap32(W[qc][2][1], W[qc][3][1]);                   \
      swap16(W[qc][0][0], W[qc][1][0]); swap16(W[qc][0][1], W[qc][1][1]);                   \
      swap16(W[qc][2][0], W[qc][3][0]); swap16(W[qc][2][1], W[qc][3][1]);                   \
    }                                                                                       \
    __builtin_amdgcn_s_setprio(1);                                                          \
    _Pragma("unroll") for (int ks = 0; ks < 2; ++ks) {                                      \
      half8 pa0 = mk8(W[0][ks * 2][0], W[0][ks * 2][1], W[0][ks * 2 + 1][0], W[0][ks * 2 + 1][1]); \
      half8 pa1 = mk8(W[1][ks * 2][0], W[1][ks * 2][1], W[1][ks * 2 + 1][0], W[1][ks * 2 + 1][1]); \
      _Pragma("unroll") for (int dt = 0; dt < 4; ++dt) {                                    \
        o[dt][0] = __builtin_amdgcn_mfma_f32_16x16x32_f16(vf[dt * 2 + ks], pa0, o[dt][0], 0, 0, 0); \
        o[dt][1] = __builtin_amdgcn_mfma_f32_16x16x32_f16(vf[dt * 2 + ks], pa1, o[dt][1], 0, 0, 0); \
      }                                                                                     \
    }                                                                                       \
    __builtin_amdgcn_s_setprio(0);                                                          \
  } while (0)

__global__ __launch_bounds__(64, 2) void attn3(const _Float16* __restrict__ qkv,
                                               const float* __restrict__ mask,
                                               const unsigned char* __restrict__ ebins,
                                               const float* __restrict__ demb,
                                               const float* __restrict__ obias,
                                               _Float16* __restrict__ aout) {
  __shared__ float elutl[128];
  const int blk = blockIdx.x;                       // 2048 blocks, 1 wave each
  const int lin = (blk & 7) * 256 + (blk >> 3);     // XCD-chunked: whole batch b on one XCD
  const int qt = lin & 31, h = (lin >> 5) & 7, b = lin >> 8;
  const int lane = threadIdx.x;
  const int lr = lane & 15, lg = lane >> 4;

  for (int e = lane; e < 128; e += 64) {
    float v;
    if (e & 64) v = -1.442695e9f;
    else v = (demb[(e & 31) * NH + h] + ((e & 32) ? 0.5f : -0.5f) * obias[h]) * 1.44269504f;
    elutl[e] = v;
  }
  __syncthreads();

  const _Float16* Qg  = qkv + (size_t)(b * NH + h) * 65536;
  const _Float16* Kg  = qkv + 4194304 + (size_t)(b * NH + h) * 65536;
  const _Float16* Vtg = qkv + 8388608 + (size_t)(b * NH + h) * 65536;

  const int q_base = qt * 32;
  half8 qf[2][2];
#pragma unroll
  for (int qc = 0; qc < 2; ++qc)
#pragma unroll
    for (int ks = 0; ks < 2; ++ks)
      qf[qc][ks] = *reinterpret_cast<const half8*>(&Qg[(q_base + qc * 16 + lr) * DH + ks * 32 + lg * 8]);
  float mq[2];
#pragma unroll
  for (int qc = 0; qc < 2; ++qc) mq[qc] = mask[b * SEQ + q_base + qc * 16 + lr];

  float m_run[2] = {-INFINITY, -INFINITY}, l_run[2] = {0.f, 0.f};
  f32x4 o[4][2] = {};

  half8 kfA[8], kfB[8];
  unsigned ewA[8], ewB[8];
  LOADKE(kfA, ewA, 0);
#pragma unroll 1
  for (int i = 0; i < 8; ++i) {
    LOADKE(kfB, ewB, 2 * i + 1);
    COMPUTE(kfA, ewA, 2 * i);
    if (i < 7) LOADKE(kfA, ewA, 2 * i + 2);
    COMPUTE(kfB, ewB, 2 * i + 1);
  }

  float linv[2];
#pragma unroll
  for (int qc = 0; qc < 2; ++qc) {
    float s_ = l_run[qc];
    s_ += __shfl_xor(s_, 16);
    s_ += __shfl_xor(s_, 32);
    linv[qc] = mq[qc] / s_;
  }
#pragma unroll
  for (int dt = 0; dt < 4; ++dt)
#pragma unroll
    for (int qc = 0; qc < 2; ++qc) {
      half4 st;
#pragma unroll
      for (int r = 0; r < 4; ++r) st[r] = (_Float16)(o[dt][qc][r] * linv[qc]);
      *reinterpret_cast<half4*>(
          &aout[(size_t)(b * SEQ + q_base + qc * 16 + lr) * 512 + h * DH + dt * 16 + lg * 4]) = st;
    }
}

// ---------------- output projection GEMM (128x128 tile, BK=64) ----------------
__global__ __launch_bounds__(256) void out_gemm2(const _Float16* __restrict__ ah,
                                                 const _Float16* __restrict__ wh,
                                                 const float* __restrict__ ob,
                                                 float* __restrict__ out) {
  __shared__ __attribute__((aligned(16))) _Float16 As[128 * 72];
  __shared__ __attribute__((aligned(16))) _Float16 Bs[128 * 72];
  const int m0 = blockIdx.x * 128, n0 = blockIdx.y * 128;
  const int tid = threadIdx.x, w = tid >> 6, lane = tid & 63;
  const int lr = lane & 15, lg = lane >> 4;
  const int wr = (w >> 1) * 64, wc = (w & 1) * 64;
  f32x4 acc[4][4] = {};
  const int srow = tid >> 1, sseg = (tid & 1) * 32;
  for (int k0 = 0; k0 < 512; k0 += 64) {
#pragma unroll
    for (int s = 0; s < 4; ++s) {
      *reinterpret_cast<uint4*>(&As[srow * 72 + sseg + s * 8]) =
          *reinterpret_cast<const uint4*>(&ah[(m0 + srow) * 512 + k0 + sseg + s * 8]);
      *reinterpret_cast<uint4*>(&Bs[srow * 72 + sseg + s * 8]) =
          *reinterpret_cast<const uint4*>(&wh[(n0 + srow) * 512 + k0 + sseg + s * 8]);
    }
    __syncthreads();
#pragma unroll
    for (int kk = 0; kk < 2; ++kk) {
      half8 af[4], bf[4];
#pragma unroll
      for (int mt = 0; mt < 4; ++mt)
        af[mt] = *reinterpret_cast<const half8*>(&As[(wr + mt * 16 + lr) * 72 + kk * 32 + lg * 8]);
#pragma unroll
      for (int nt = 0; nt < 4; ++nt)
        bf[nt] = *reinterpret_cast<const half8*>(&Bs[(wc + nt * 16 + lr) * 72 + kk * 32 + lg * 8]);
#pragma unroll
      for (int mt = 0; mt < 4; ++mt)
#pragma unroll
        for (int nt = 0; nt < 4; ++nt)
          acc[mt][nt] = __builtin_amdgcn_mfma_f32_16x16x32_f16(af[mt], bf[nt], acc[mt][nt], 0, 0, 0);
    }
    __syncthreads();
  }
#pragma unroll
  for (int nt = 0; nt < 4; ++nt) {
    int n = n0 + wc + nt * 16 + lr;
    float bv = ob[n];
#pragma unroll
    for (int mt = 0; mt < 4; ++mt)
#pragma unroll
      for (int r = 0; r < 4; ++r) {
        int m = m0 + wr + mt * 16 + lg * 4 + r;
        out[m * 512 + n] = acc[mt][nt][r] + bv;
      }
  }
}

extern "C" void kernel_launch(void* const* d_in, const int* in_sizes, int n_in,
                              void* d_out, int out_size, void* d_ws, size_t ws_size,
                              hipStream_t stream) {
  const float* x         = (const float*)d_in[0];
  const int*   positions = (const int*)d_in[1];
  const float* mask      = (const float*)d_in[2];
  const float* qw        = (const float*)d_in[3];
  const float* qb        = (const float*)d_in[4];
  const float* kw        = (const float*)d_in[5];
  const float* kb        = (const float*)d_in[6];
  const float* vw        = (const float*)d_in[7];
  const float* vb        = (const float*)d_in[8];
  const float* ow        = (const float*)d_in[9];
  const float* ob        = (const float*)d_in[10];
  const float* demb      = (const float*)d_in[11];
  const float* obias     = (const float*)d_in[12];
  const float* edges     = (const float*)d_in[13];

  char* ws = (char*)d_ws;
  _Float16* xh        = (_Float16*)(ws);                  // [0, 8M) — dead after qkv_gemm2
  unsigned char* ebins = (unsigned char*)(ws);            // reuses xh region after qkv_gemm2
  _Float16* qkv       = (_Float16*)(ws + 8388608);        // Q*0.125 | K*log2e | V^T  (24 MB)
  _Float16* aouth     = (_Float16*)(ws + 33554432);       // 8 MB
  _Float16* wqkvh     = (_Float16*)(ws + 41943040);       // 1.5 MB
  _Float16* owh       = (_Float16*)(ws + 43515904);       // 0.5 MB
  float*    qkvbias   = (float*)(ws + 44040192);          // 6 KB
  unsigned char* lutd = (unsigned char*)(ws + 44046336);  // 5120 B
  float*    outp      = (float*)d_out;

  prep_all<<<5142, 256, 0, stream>>>(x, qw, kw, vw, ow, qb, kb, vb, edges,
                                     xh, wqkvh, owh, qkvbias, lutd);
  qkv_gemm2<<<dim3(64, 12), 256, 0, stream>>>(xh, wqkvh, qkvbias, qkv);
  prep_ebins<<<2048, 256, 0, stream>>>(positions, mask, lutd, ebins);  // overwrites xh region
  attn3<<<2048, 64, 0, stream>>>(qkv, mask, ebins, demb, obias, aouth);
  out_gemm2<<<dim3(64, 4), 256, 0, stream>>>(aouth, owh, ob, outp);
}

// Round 5
// 127.461 us; speedup vs baseline: 1.3145x; 1.3145x over previous
//
#include <hip/hip_runtime.h>
#include <hip/hip_bf16.h>

#define SEQ   1024
#define NH    8
#define DH    64

typedef __attribute__((ext_vector_type(8))) _Float16 half8;
typedef __attribute__((ext_vector_type(4))) _Float16 half4;
typedef __attribute__((ext_vector_type(4))) float    f32x4;

#if __has_builtin(__builtin_amdgcn_exp2f)
#define EXP2F __builtin_amdgcn_exp2f
#else
#define EXP2F exp2f
#endif

__device__ inline unsigned pk2(float a, float b) {
  return __builtin_bit_cast(unsigned, __builtin_amdgcn_cvt_pkrtz(a, b));
}
__device__ inline void swap32(unsigned &a, unsigned &b) {
  asm("v_permlane32_swap_b32 %0, %1" : "+v"(a), "+v"(b));
}
__device__ inline void swap16(unsigned &a, unsigned &b) {
  asm("v_permlane16_swap_b32 %0, %1" : "+v"(a), "+v"(b));
}
__device__ inline half8 mk8(unsigned a, unsigned b, unsigned c, unsigned d) {
  union { unsigned u[4]; half8 h; } x;
  x.u[0] = a; x.u[1] = b; x.u[2] = c; x.u[3] = d;
  return x.h;
}

// ---------------- merged prep: cast x, weights, bias concat, dist->bin LUT ----------------
__global__ void prep_all(const float* __restrict__ x,
                         const float* __restrict__ qw, const float* __restrict__ kw,
                         const float* __restrict__ vw, const float* __restrict__ ow,
                         const float* __restrict__ qb, const float* __restrict__ kb,
                         const float* __restrict__ vb, const float* __restrict__ edges,
                         _Float16* __restrict__ xh, _Float16* __restrict__ wqkvh,
                         _Float16* __restrict__ owh, float* __restrict__ qkvbias,
                         unsigned char* __restrict__ lutd) {
  const int blk = blockIdx.x, tid = threadIdx.x;
  if (blk < 4096) {
    int g = blk * 256 + tid;
    float4 v = reinterpret_cast<const float4*>(x)[g];
    half4 u;
    u[0] = (_Float16)v.x; u[1] = (_Float16)v.y; u[2] = (_Float16)v.z; u[3] = (_Float16)v.w;
    reinterpret_cast<half4*>(xh)[g] = u;
  } else if (blk < 5122) {
    int g = (blk - 4096) * 256 + tid;
    if (g < 196608) {
      const float* src = (g < 65536) ? qw : (g < 131072) ? kw : vw;
      int lg = g & 65535;
      float4 v = reinterpret_cast<const float4*>(src)[lg];
      half4 u;
      u[0] = (_Float16)v.x; u[1] = (_Float16)v.y; u[2] = (_Float16)v.z; u[3] = (_Float16)v.w;
      reinterpret_cast<half4*>(wqkvh)[g] = u;
    } else if (g < 262144) {
      int lg = g - 196608;
      float4 v = reinterpret_cast<const float4*>(ow)[lg];
      half4 u;
      u[0] = (_Float16)v.x; u[1] = (_Float16)v.y; u[2] = (_Float16)v.z; u[3] = (_Float16)v.w;
      reinterpret_cast<half4*>(owh)[lg] = u;
    } else if (g < 262528) {
      int lg = g - 262144;
      const float* src = (lg < 128) ? qb : (lg < 256) ? kb : vb;
      int ll = lg & 127;
      reinterpret_cast<float4*>(qkvbias)[lg] = reinterpret_cast<const float4*>(src)[ll];
    }
  } else {
    int d = (blk - 5122) * 256 + tid;   // 0..5119
    float fd = (float)d;
    int bin = 0;
#pragma unroll
    for (int t = 0; t < 31; ++t) bin += (edges[t] < fd) ? 1 : 0;
    lutd[d] = (unsigned char)bin;
  }
}

// ---------------- prep: ebins[b][r][c] = bin | (p_c>p_r)<<5 | (mask_c==0)<<6 ----------------
__global__ __launch_bounds__(256) void prep_ebins(const int* __restrict__ positions,
                                                  const float* __restrict__ mask,
                                                  const unsigned char* __restrict__ lutd,
                                                  unsigned char* __restrict__ ebins) {
  __shared__ unsigned char lutl[5120];
  __shared__ int posl[SEQ];
  __shared__ unsigned char mk[SEQ];
  const int b = blockIdx.x >> 8, j0 = (blockIdx.x & 255) * 4;
  const int tid = threadIdx.x;
  for (int i = tid; i < 1280; i += 256)
    reinterpret_cast<unsigned*>(lutl)[i] = reinterpret_cast<const unsigned*>(lutd)[i];
  for (int i = tid; i < SEQ; i += 256) {
    posl[i] = positions[b * SEQ + i];
    mk[i] = (mask[b * SEQ + i] == 0.f) ? 64 : 0;
  }
  __syncthreads();
  const int c0 = tid * 4;
#pragma unroll
  for (int jj = 0; jj < 4; ++jj) {
    const int j = j0 + jj;
    const int pr = posl[j];
    unsigned out = 0;
#pragma unroll
    for (int r = 0; r < 4; ++r) {
      int c = c0 + r;
      int pc = posl[c];
      int d = pc - pr; d = d < 0 ? -d : d;
      if (d > 5119) d = 5119;
      unsigned e = lutl[d] | ((pc > pr) ? 32u : 0u) | (unsigned)mk[c];
      out |= e << (8 * r);
    }
    reinterpret_cast<unsigned*>(&ebins[(size_t)(b * SEQ + j) * SEQ])[tid] = out;
  }
}

// ---------------- QKV projection GEMM (128x128 tile, BK=64) ----------------
// Q -> [b][h][n][d] * 0.125 ; K -> [b][h][n][d] * log2(e) ; V -> transposed [b][h][d][n]
__global__ __launch_bounds__(256) void qkv_gemm2(const _Float16* __restrict__ xh,
                                                 const _Float16* __restrict__ wh,
                                                 const float* __restrict__ bias,
                                                 _Float16* __restrict__ qkv) {
  __shared__ __attribute__((aligned(16))) _Float16 As[128 * 72];
  __shared__ __attribute__((aligned(16))) _Float16 Bs[128 * 72];
  const int m0 = blockIdx.x * 128, n0 = blockIdx.y * 128;
  const int tid = threadIdx.x, w = tid >> 6, lane = tid & 63;
  const int lr = lane & 15, lg = lane >> 4;
  const int wr = (w >> 1) * 64, wc = (w & 1) * 64;
  f32x4 acc[4][4] = {};
  const int srow = tid >> 1, sseg = (tid & 1) * 32;
  for (int k0 = 0; k0 < 512; k0 += 64) {
#pragma unroll
    for (int s = 0; s < 4; ++s) {
      *reinterpret_cast<uint4*>(&As[srow * 72 + sseg + s * 8]) =
          *reinterpret_cast<const uint4*>(&xh[(m0 + srow) * 512 + k0 + sseg + s * 8]);
      *reinterpret_cast<uint4*>(&Bs[srow * 72 + sseg + s * 8]) =
          *reinterpret_cast<const uint4*>(&wh[(n0 + srow) * 512 + k0 + sseg + s * 8]);
    }
    __syncthreads();
#pragma unroll
    for (int kk = 0; kk < 2; ++kk) {
      half8 af[4], bf[4];
#pragma unroll
      for (int mt = 0; mt < 4; ++mt)
        af[mt] = *reinterpret_cast<const half8*>(&As[(wr + mt * 16 + lr) * 72 + kk * 32 + lg * 8]);
#pragma unroll
      for (int nt = 0; nt < 4; ++nt)
        bf[nt] = *reinterpret_cast<const half8*>(&Bs[(wc + nt * 16 + lr) * 72 + kk * 32 + lg * 8]);
#pragma unroll
      for (int mt = 0; mt < 4; ++mt)
#pragma unroll
        for (int nt = 0; nt < 4; ++nt)
          acc[mt][nt] = __builtin_amdgcn_mfma_f32_16x16x32_f16(af[mt], bf[nt], acc[mt][nt], 0, 0, 0);
    }
    __syncthreads();
  }
  const int p = n0 >> 9;   // block-uniform: 0=Q,1=K,2=V
  const float scl = (p == 0) ? 0.125f : (p == 1) ? 1.44269504f : 1.0f;
  if (p < 2) {
#pragma unroll
    for (int nt = 0; nt < 4; ++nt) {
      int n = n0 + wc + nt * 16 + lr;
      float bv = bias[n];
      int c = n & 511, h = c >> 6, d = c & 63;
#pragma unroll
      for (int mt = 0; mt < 4; ++mt)
#pragma unroll
        for (int r = 0; r < 4; ++r) {
          int m = m0 + wr + mt * 16 + lg * 4 + r;
          int bb = m >> 10, nn = m & 1023;
          qkv[p * 4194304 + ((bb * NH + h) * SEQ + nn) * DH + d] = (_Float16)((acc[mt][nt][r] + bv) * scl);
        }
    }
  } else {
#pragma unroll
    for (int nt = 0; nt < 4; ++nt) {
      int n = n0 + wc + nt * 16 + lr;
      float bv = bias[n];
      int c = n & 511, h = c >> 6, d = c & 63;
#pragma unroll
      for (int mt = 0; mt < 4; ++mt) {
        int m = m0 + wr + mt * 16 + lg * 4;
        int bb = m >> 10, nn = m & 1023;
        half4 st;
#pragma unroll
        for (int r = 0; r < 4; ++r) st[r] = (_Float16)(acc[mt][nt][r] + bv);
        *reinterpret_cast<half4*>(&qkv[8388608 + ((bb * NH + h) * DH + d) * SEQ + nn]) = st;
      }
    }
  }
}

// ---------------- fused attention: split-K in-block (2 streams x 4 waves), LDS dbuf ----------------
// q-tile 128 rows/block; waves 0-3: k in [0,512), waves 4-7: k in [512,1024); merge via LDS.
__global__ __launch_bounds__(512, 4) void attn4(const _Float16* __restrict__ qkv,
                                                const float* __restrict__ mask,
                                                const unsigned char* __restrict__ ebins,
                                                const float* __restrict__ demb,
                                                const float* __restrict__ obias,
                                                _Float16* __restrict__ aout) {
  __shared__ __attribute__((aligned(16))) char smem[74240];
  _Float16* const Ks0 = (_Float16*)smem;                 // [strm][buf][64*72]  36,864 B
  _Float16* const Vt0 = (_Float16*)(smem + 36864);       // [strm][buf][64*72]  36,864 B
  float*    const elutl = (float*)(smem + 73728);        // 128 f32
  float*    const obuf  = (float*)smem;                  // combine overlay [4][64][33]
  float*    const mlbuf = (float*)smem + 8448;           // [4][2][16][2]

  const int blk = blockIdx.x;                     // 512 blocks
  const int lin = (blk & 7) * 64 + (blk >> 3);    // XCD-chunked: one batch b per XCD
  const int qt = lin & 7, h = (lin >> 3) & 7, b = lin >> 6;
  const int tid = threadIdx.x, w = tid >> 6, lane = tid & 63;
  const int lr = lane & 15, lg = lane >> 4;
  const int strm = w >> 2, wq = w & 3;

  if (tid < 128) {
    float v;
    if (tid & 64) v = -1.442695e9f;
    else v = (demb[(tid & 31) * NH + h] + ((tid & 32) ? 0.5f : -0.5f) * obias[h]) * 1.44269504f;
    elutl[tid] = v;
  }

  const _Float16* Qg  = qkv + (size_t)(b * NH + h) * 65536;
  const _Float16* Kg  = qkv + 4194304 + (size_t)(b * NH + h) * 65536;
  const _Float16* Vtg = qkv + 8388608 + (size_t)(b * NH + h) * 65536;

  const int q_base = qt * 128 + wq * 32;
  half8 qf[2][2];
#pragma unroll
  for (int qc = 0; qc < 2; ++qc)
#pragma unroll
    for (int ks = 0; ks < 2; ++ks)
      qf[qc][ks] = *reinterpret_cast<const half8*>(&Qg[(q_base + qc * 16 + lr) * DH + ks * 32 + lg * 8]);
  float mq[2];
#pragma unroll
  for (int qc = 0; qc < 2; ++qc) mq[qc] = mask[b * SEQ + q_base + qc * 16 + lr];

  float m_run[2] = {-INFINITY, -INFINITY}, l_run[2] = {0.f, 0.f};
  f32x4 o[4][2] = {};

  const int stid = tid & 255;                 // staging threads of this stream (tid>>8 == strm)
  const int sr = stid >> 2, sc = (stid & 3) * 16;
  _Float16* const KsA = Ks0 + (strm * 2) * 4608;
  _Float16* const KsB = Ks0 + (strm * 2 + 1) * 4608;
  _Float16* const VtA = Vt0 + (strm * 2) * 4608;
  _Float16* const VtB = Vt0 + (strm * 2 + 1) * 4608;
  {
    const int kv0 = strm * 512;
    *reinterpret_cast<uint4*>(&KsA[sr * 72 + sc]) =
        *reinterpret_cast<const uint4*>(&Kg[(kv0 + sr) * DH + sc]);
    *reinterpret_cast<uint4*>(&KsA[sr * 72 + sc + 8]) =
        *reinterpret_cast<const uint4*>(&Kg[(kv0 + sr) * DH + sc + 8]);
    *reinterpret_cast<uint4*>(&VtA[sr * 72 + sc]) =
        *reinterpret_cast<const uint4*>(&Vtg[sr * SEQ + kv0 + sc]);
    *reinterpret_cast<uint4*>(&VtA[sr * 72 + sc + 8]) =
        *reinterpret_cast<const uint4*>(&Vtg[sr * SEQ + kv0 + sc + 8]);
  }
  __syncthreads();

#pragma unroll 1
  for (int i = 0; i < 8; ++i) {
    const int cur = i & 1;
    const int kt = strm * 8 + i;
    const _Float16* Ksc = cur ? KsB : KsA;
    const _Float16* Vtc = cur ? VtB : VtA;
    _Float16* Ksn = cur ? KsA : KsB;
    _Float16* Vtn = cur ? VtA : VtB;
    // (a) issue next-tile global loads early
    uint4 kA, kB, vA, vB;
    if (i < 7) {
      const int kv = (kt + 1) * 64;
      kA = *reinterpret_cast<const uint4*>(&Kg[(kv + sr) * DH + sc]);
      kB = *reinterpret_cast<const uint4*>(&Kg[(kv + sr) * DH + sc + 8]);
      vA = *reinterpret_cast<const uint4*>(&Vtg[sr * SEQ + kv + sc]);
      vB = *reinterpret_cast<const uint4*>(&Vtg[sr * SEQ + kv + sc + 8]);
    }
    // (b) accumulator init from ebin bytes (bias+sign+mask, exp2-scaled)
    f32x4 s4t[4][2];
#pragma unroll
    for (int ct = 0; ct < 4; ++ct)
#pragma unroll
      for (int qc = 0; qc < 2; ++qc) {
        unsigned ebw = *reinterpret_cast<const unsigned*>(
            &ebins[(size_t)(b * SEQ + q_base + qc * 16 + lr) * SEQ + kt * 64 + ct * 16 + lg * 4]);
        s4t[ct][qc][0] = elutl[ebw & 127u];
        s4t[ct][qc][1] = elutl[(ebw >> 8) & 127u];
        s4t[ct][qc][2] = elutl[(ebw >> 16) & 127u];
        s4t[ct][qc][3] = elutl[(ebw >> 24) & 127u];
      }
    // QK^T swapped: S^T tile, row=k col=q
    __builtin_amdgcn_s_setprio(1);
#pragma unroll
    for (int ct = 0; ct < 4; ++ct) {
      half8 kf0 = *reinterpret_cast<const half8*>(&Ksc[(ct * 16 + lr) * 72 + lg * 8]);
      half8 kf1 = *reinterpret_cast<const half8*>(&Ksc[(ct * 16 + lr) * 72 + 32 + lg * 8]);
#pragma unroll
      for (int qc = 0; qc < 2; ++qc) {
        s4t[ct][qc] = __builtin_amdgcn_mfma_f32_16x16x32_f16(kf0, qf[qc][0], s4t[ct][qc], 0, 0, 0);
        s4t[ct][qc] = __builtin_amdgcn_mfma_f32_16x16x32_f16(kf1, qf[qc][1], s4t[ct][qc], 0, 0, 0);
      }
    }
    __builtin_amdgcn_s_setprio(0);
    // online softmax with defer-max; l kept lg-partial
    unsigned W[2][4][2];
#pragma unroll
    for (int qc = 0; qc < 2; ++qc) {
      float a0 = fmaxf(fmaxf(s4t[0][qc][0], s4t[0][qc][1]), fmaxf(s4t[0][qc][2], s4t[0][qc][3]));
      float a1 = fmaxf(fmaxf(s4t[1][qc][0], s4t[1][qc][1]), fmaxf(s4t[1][qc][2], s4t[1][qc][3]));
      float a2 = fmaxf(fmaxf(s4t[2][qc][0], s4t[2][qc][1]), fmaxf(s4t[2][qc][2], s4t[2][qc][3]));
      float a3 = fmaxf(fmaxf(s4t[3][qc][0], s4t[3][qc][1]), fmaxf(s4t[3][qc][2], s4t[3][qc][3]));
      float pm = fmaxf(fmaxf(a0, a1), fmaxf(a2, a3));
      pm = fmaxf(pm, __shfl_xor(pm, 16));
      pm = fmaxf(pm, __shfl_xor(pm, 32));
      if (__any((int)(pm > m_run[qc] + 8.0f))) {
        float newm = fmaxf(m_run[qc], pm);
        float alpha = EXP2F(m_run[qc] - newm);
        m_run[qc] = newm; l_run[qc] *= alpha;
#pragma unroll
        for (int dt = 0; dt < 4; ++dt) o[dt][qc] *= alpha;
      }
      float ss_ = 0.f;
#pragma unroll
      for (int ct = 0; ct < 4; ++ct)
#pragma unroll
        for (int r = 0; r < 4; ++r) {
          float pv = EXP2F(s4t[ct][qc][r] - m_run[qc]);
          s4t[ct][qc][r] = pv; ss_ += pv;
        }
      l_run[qc] += ss_;
#pragma unroll
      for (int ct = 0; ct < 4; ++ct) {
        W[qc][ct][0] = pk2(s4t[ct][qc][0], s4t[ct][qc][1]);
        W[qc][ct][1] = pk2(s4t[ct][qc][2], s4t[ct][qc][3]);
      }
      swap32(W[qc][0][0], W[qc][1][0]); swap32(W[qc][0][1], W[qc][1][1]);
      swap32(W[qc][2][0], W[qc][3][0]); swap32(W[qc][2][1], W[qc][3][1]);
      swap16(W[qc][0][0], W[qc][1][0]); swap16(W[qc][0][1], W[qc][1][1]);
      swap16(W[qc][2][0], W[qc][3][0]); swap16(W[qc][2][1], W[qc][3][1]);
    }
    // (c) write next tile to other LDS buffer
    if (i < 7) {
      *reinterpret_cast<uint4*>(&Ksn[sr * 72 + sc]) = kA;
      *reinterpret_cast<uint4*>(&Ksn[sr * 72 + sc + 8]) = kB;
      *reinterpret_cast<uint4*>(&Vtn[sr * 72 + sc]) = vA;
      *reinterpret_cast<uint4*>(&Vtn[sr * 72 + sc + 8]) = vB;
    }
    // (d) PV swapped: o^T[d][q] += Vt-frag x P-frag
    __builtin_amdgcn_s_setprio(1);
#pragma unroll
    for (int ks = 0; ks < 2; ++ks) {
      half8 pa0 = mk8(W[0][ks * 2][0], W[0][ks * 2][1], W[0][ks * 2 + 1][0], W[0][ks * 2 + 1][1]);
      half8 pa1 = mk8(W[1][ks * 2][0], W[1][ks * 2][1], W[1][ks * 2 + 1][0], W[1][ks * 2 + 1][1]);
#pragma unroll
      for (int dt = 0; dt < 4; ++dt) {
        half8 vf = *reinterpret_cast<const half8*>(&Vtc[(dt * 16 + lr) * 72 + ks * 32 + lg * 8]);
        o[dt][0] = __builtin_amdgcn_mfma_f32_16x16x32_f16(vf, pa0, o[dt][0], 0, 0, 0);
        o[dt][1] = __builtin_amdgcn_mfma_f32_16x16x32_f16(vf, pa1, o[dt][1], 0, 0, 0);
      }
    }
    __builtin_amdgcn_s_setprio(0);
    __syncthreads();
  }

  // ---- split-K combine via LDS ----
  float L[2];
#pragma unroll
  for (int qc = 0; qc < 2; ++qc) {
    float s_ = l_run[qc];
    s_ += __shfl_xor(s_, 16);
    s_ += __shfl_xor(s_, 32);
    L[qc] = s_;
  }
  if (strm == 1) {
#pragma unroll
    for (int qc = 0; qc < 2; ++qc) {
#pragma unroll
      for (int dt = 0; dt < 4; ++dt)
#pragma unroll
        for (int r = 0; r < 4; ++r)
          obuf[(wq * 64 + dt * 16 + lg * 4 + r) * 33 + qc * 16 + lr] = o[dt][qc][r];
      if (lg == 0) {
        int mb = ((wq * 2 + qc) * 16 + lr) * 2;
        mlbuf[mb] = m_run[qc];
        mlbuf[mb + 1] = L[qc];
      }
    }
  }
  __syncthreads();
  if (strm == 0) {
#pragma unroll
    for (int qc = 0; qc < 2; ++qc) {
      int mb = ((wq * 2 + qc) * 16 + lr) * 2;
      float m1 = mlbuf[mb], L1 = mlbuf[mb + 1];
      float mstar = fmaxf(m_run[qc], m1);
      float aa0 = EXP2F(m_run[qc] - mstar), aa1 = EXP2F(m1 - mstar);
      float lst = L[qc] * aa0 + L1 * aa1;
      float linv = mq[qc] / lst;
#pragma unroll
      for (int dt = 0; dt < 4; ++dt) {
        half4 st;
#pragma unroll
        for (int r = 0; r < 4; ++r) {
          float o1 = obuf[(wq * 64 + dt * 16 + lg * 4 + r) * 33 + qc * 16 + lr];
          st[r] = (_Float16)((o[dt][qc][r] * aa0 + o1 * aa1) * linv);
        }
        *reinterpret_cast<half4*>(
            &aout[(size_t)(b * SEQ + q_base + qc * 16 + lr) * 512 + h * DH + dt * 16 + lg * 4]) = st;
      }
    }
  }
}

// ---------------- output projection GEMM (128x128 tile, BK=64) ----------------
__global__ __launch_bounds__(256) void out_gemm2(const _Float16* __restrict__ ah,
                                                 const _Float16* __restrict__ wh,
                                                 const float* __restrict__ ob,
                                                 float* __restrict__ out) {
  __shared__ __attribute__((aligned(16))) _Float16 As[128 * 72];
  __shared__ __attribute__((aligned(16))) _Float16 Bs[128 * 72];
  const int m0 = blockIdx.x * 128, n0 = blockIdx.y * 128;
  const int tid = threadIdx.x, w = tid >> 6, lane = tid & 63;
  const int lr = lane & 15, lg = lane >> 4;
  const int wr = (w >> 1) * 64, wc = (w & 1) * 64;
  f32x4 acc[4][4] = {};
  const int srow = tid >> 1, sseg = (tid & 1) * 32;
  for (int k0 = 0; k0 < 512; k0 += 64) {
#pragma unroll
    for (int s = 0; s < 4; ++s) {
      *reinterpret_cast<uint4*>(&As[srow * 72 + sseg + s * 8]) =
          *reinterpret_cast<const uint4*>(&ah[(m0 + srow) * 512 + k0 + sseg + s * 8]);
      *reinterpret_cast<uint4*>(&Bs[srow * 72 + sseg + s * 8]) =
          *reinterpret_cast<const uint4*>(&wh[(n0 + srow) * 512 + k0 + sseg + s * 8]);
    }
    __syncthreads();
#pragma unroll
    for (int kk = 0; kk < 2; ++kk) {
      half8 af[4], bf[4];
#pragma unroll
      for (int mt = 0; mt < 4; ++mt)
        af[mt] = *reinterpret_cast<const half8*>(&As[(wr + mt * 16 + lr) * 72 + kk * 32 + lg * 8]);
#pragma unroll
      for (int nt = 0; nt < 4; ++nt)
        bf[nt] = *reinterpret_cast<const half8*>(&Bs[(wc + nt * 16 + lr) * 72 + kk * 32 + lg * 8]);
#pragma unroll
      for (int mt = 0; mt < 4; ++mt)
#pragma unroll
        for (int nt = 0; nt < 4; ++nt)
          acc[mt][nt] = __builtin_amdgcn_mfma_f32_16x16x32_f16(af[mt], bf[nt], acc[mt][nt], 0, 0, 0);
    }
    __syncthreads();
  }
#pragma unroll
  for (int nt = 0; nt < 4; ++nt) {
    int n = n0 + wc + nt * 16 + lr;
    float bv = ob[n];
#pragma unroll
    for (int mt = 0; mt < 4; ++mt)
#pragma unroll
      for (int r = 0; r < 4; ++r) {
        int m = m0 + wr + mt * 16 + lg * 4 + r;
        out[m * 512 + n] = acc[mt][nt][r] + bv;
      }
  }
}

extern "C" void kernel_launch(void* const* d_in, const int* in_sizes, int n_in,
                              void* d_out, int out_size, void* d_ws, size_t ws_size,
                              hipStream_t stream) {
  const float* x         = (const float*)d_in[0];
  const int*   positions = (const int*)d_in[1];
  const float* mask      = (const float*)d_in[2];
  const float* qw        = (const float*)d_in[3];
  const float* qb        = (const float*)d_in[4];
  const float* kw        = (const float*)d_in[5];
  const float* kb        = (const float*)d_in[6];
  const float* vw        = (const float*)d_in[7];
  const float* vb        = (const float*)d_in[8];
  const float* ow        = (const float*)d_in[9];
  const float* ob        = (const float*)d_in[10];
  const float* demb      = (const float*)d_in[11];
  const float* obias     = (const float*)d_in[12];
  const float* edges     = (const float*)d_in[13];

  char* ws = (char*)d_ws;
  _Float16* xh        = (_Float16*)(ws);                  // [0, 8M) — dead after qkv_gemm2
  unsigned char* ebins = (unsigned char*)(ws);            // reuses xh region after qkv_gemm2
  _Float16* qkv       = (_Float16*)(ws + 8388608);        // Q*0.125 | K*log2e | V^T  (24 MB)
  _Float16* aouth     = (_Float16*)(ws + 33554432);       // 8 MB
  _Float16* wqkvh     = (_Float16*)(ws + 41943040);       // 1.5 MB
  _Float16* owh       = (_Float16*)(ws + 43515904);       // 0.5 MB
  float*    qkvbias   = (float*)(ws + 44040192);          // 6 KB
  unsigned char* lutd = (unsigned char*)(ws + 44046336);  // 5120 B
  float*    outp      = (float*)d_out;

  prep_all<<<5142, 256, 0, stream>>>(x, qw, kw, vw, ow, qb, kb, vb, edges,
                                     xh, wqkvh, owh, qkvbias, lutd);
  qkv_gemm2<<<dim3(64, 12), 256, 0, stream>>>(xh, wqkvh, qkvbias, qkv);
  prep_ebins<<<2048, 256, 0, stream>>>(positions, mask, lutd, ebins);  // overwrites xh region
  attn4<<<512, 512, 0, stream>>>(qkv, mask, ebins, demb, obias, aouth);
  out_gemm2<<<dim3(64, 4), 256, 0, stream>>>(aouth, owh, ob, outp);
}

// Round 6
// 109.854 us; speedup vs baseline: 1.5252x; 1.1603x over previous
//
#include <hip/hip_runtime.h>
#include <hip/hip_bf16.h>

#define SEQ   1024
#define NH    8
#define DH    64

typedef __attribute__((ext_vector_type(8))) _Float16 half8;
typedef __attribute__((ext_vector_type(4))) _Float16 half4;
typedef __attribute__((ext_vector_type(4))) float    f32x4;

#if __has_builtin(__builtin_amdgcn_exp2f)
#define EXP2F __builtin_amdgcn_exp2f
#else
#define EXP2F exp2f
#endif

__device__ inline unsigned pk2(float a, float b) {
  return __builtin_bit_cast(unsigned, __builtin_amdgcn_cvt_pkrtz(a, b));
}
__device__ inline void swap32(unsigned &a, unsigned &b) {
  asm("v_permlane32_swap_b32 %0, %1" : "+v"(a), "+v"(b));
}
__device__ inline void swap16(unsigned &a, unsigned &b) {
  asm("v_permlane16_swap_b32 %0, %1" : "+v"(a), "+v"(b));
}
__device__ inline half8 mk8(unsigned a, unsigned b, unsigned c, unsigned d) {
  union { unsigned u[4]; half8 h; } x;
  x.u[0] = a; x.u[1] = b; x.u[2] = c; x.u[3] = d;
  return x.h;
}

// ---------------- merged prep: cast x, weights, bias concat, dist->bin LUT ----------------
__global__ void prep_all(const float* __restrict__ x,
                         const float* __restrict__ qw, const float* __restrict__ kw,
                         const float* __restrict__ vw, const float* __restrict__ ow,
                         const float* __restrict__ qb, const float* __restrict__ kb,
                         const float* __restrict__ vb, const float* __restrict__ edges,
                         _Float16* __restrict__ xh, _Float16* __restrict__ wqkvh,
                         _Float16* __restrict__ owh, float* __restrict__ qkvbias,
                         unsigned char* __restrict__ lutd) {
  const int blk = blockIdx.x, tid = threadIdx.x;
  if (blk < 4096) {
    int g = blk * 256 + tid;
    float4 v = reinterpret_cast<const float4*>(x)[g];
    half4 u;
    u[0] = (_Float16)v.x; u[1] = (_Float16)v.y; u[2] = (_Float16)v.z; u[3] = (_Float16)v.w;
    reinterpret_cast<half4*>(xh)[g] = u;
  } else if (blk < 5122) {
    int g = (blk - 4096) * 256 + tid;
    if (g < 196608) {
      const float* src = (g < 65536) ? qw : (g < 131072) ? kw : vw;
      int lg = g & 65535;
      float4 v = reinterpret_cast<const float4*>(src)[lg];
      half4 u;
      u[0] = (_Float16)v.x; u[1] = (_Float16)v.y; u[2] = (_Float16)v.z; u[3] = (_Float16)v.w;
      reinterpret_cast<half4*>(wqkvh)[g] = u;
    } else if (g < 262144) {
      int lg = g - 196608;
      float4 v = reinterpret_cast<const float4*>(ow)[lg];
      half4 u;
      u[0] = (_Float16)v.x; u[1] = (_Float16)v.y; u[2] = (_Float16)v.z; u[3] = (_Float16)v.w;
      reinterpret_cast<half4*>(owh)[lg] = u;
    } else if (g < 262528) {
      int lg = g - 262144;
      const float* src = (lg < 128) ? qb : (lg < 256) ? kb : vb;
      int ll = lg & 127;
      reinterpret_cast<float4*>(qkvbias)[lg] = reinterpret_cast<const float4*>(src)[ll];
    }
  } else {
    int d = (blk - 5122) * 256 + tid;   // 0..5119
    float fd = (float)d;
    int bin = 0;
#pragma unroll
    for (int t = 0; t < 31; ++t) bin += (edges[t] < fd) ? 1 : 0;
    lutd[d] = (unsigned char)bin;
  }
}

// ---------------- prep: ebins[b][r][c] = bin | (p_c>p_r)<<5 | (mask_c==0)<<6 ----------------
__global__ __launch_bounds__(256) void prep_ebins(const int* __restrict__ positions,
                                                  const float* __restrict__ mask,
                                                  const unsigned char* __restrict__ lutd,
                                                  unsigned char* __restrict__ ebins) {
  __shared__ unsigned char lutl[5120];
  __shared__ int posl[SEQ];
  __shared__ unsigned char mk[SEQ];
  const int b = blockIdx.x >> 8, j0 = (blockIdx.x & 255) * 4;
  const int tid = threadIdx.x;
  for (int i = tid; i < 1280; i += 256)
    reinterpret_cast<unsigned*>(lutl)[i] = reinterpret_cast<const unsigned*>(lutd)[i];
  for (int i = tid; i < SEQ; i += 256) {
    posl[i] = positions[b * SEQ + i];
    mk[i] = (mask[b * SEQ + i] == 0.f) ? 64 : 0;
  }
  __syncthreads();
  const int c0 = tid * 4;
#pragma unroll
  for (int jj = 0; jj < 4; ++jj) {
    const int j = j0 + jj;
    const int pr = posl[j];
    unsigned out = 0;
#pragma unroll
    for (int r = 0; r < 4; ++r) {
      int c = c0 + r;
      int pc = posl[c];
      int d = pc - pr; d = d < 0 ? -d : d;
      if (d > 5119) d = 5119;
      unsigned e = lutl[d] | ((pc > pr) ? 32u : 0u) | (unsigned)mk[c];
      out |= e << (8 * r);
    }
    reinterpret_cast<unsigned*>(&ebins[(size_t)(b * SEQ + j) * SEQ])[tid] = out;
  }
}

// ---------------- QKV projection GEMM (128x128 tile, BK=64) ----------------
// Q -> [b][h][n][d] * 0.125 ; K -> [b][h][n][d] * log2(e) ; V -> transposed [b][h][d][n]
__global__ __launch_bounds__(256) void qkv_gemm2(const _Float16* __restrict__ xh,
                                                 const _Float16* __restrict__ wh,
                                                 const float* __restrict__ bias,
                                                 _Float16* __restrict__ qkv) {
  __shared__ __attribute__((aligned(16))) _Float16 As[128 * 72];
  __shared__ __attribute__((aligned(16))) _Float16 Bs[128 * 72];
  const int m0 = blockIdx.x * 128, n0 = blockIdx.y * 128;
  const int tid = threadIdx.x, w = tid >> 6, lane = tid & 63;
  const int lr = lane & 15, lg = lane >> 4;
  const int wr = (w >> 1) * 64, wc = (w & 1) * 64;
  f32x4 acc[4][4] = {};
  const int srow = tid >> 1, sseg = (tid & 1) * 32;
  for (int k0 = 0; k0 < 512; k0 += 64) {
#pragma unroll
    for (int s = 0; s < 4; ++s) {
      *reinterpret_cast<uint4*>(&As[srow * 72 + sseg + s * 8]) =
          *reinterpret_cast<const uint4*>(&xh[(m0 + srow) * 512 + k0 + sseg + s * 8]);
      *reinterpret_cast<uint4*>(&Bs[srow * 72 + sseg + s * 8]) =
          *reinterpret_cast<const uint4*>(&wh[(n0 + srow) * 512 + k0 + sseg + s * 8]);
    }
    __syncthreads();
#pragma unroll
    for (int kk = 0; kk < 2; ++kk) {
      half8 af[4], bf[4];
#pragma unroll
      for (int mt = 0; mt < 4; ++mt)
        af[mt] = *reinterpret_cast<const half8*>(&As[(wr + mt * 16 + lr) * 72 + kk * 32 + lg * 8]);
#pragma unroll
      for (int nt = 0; nt < 4; ++nt)
        bf[nt] = *reinterpret_cast<const half8*>(&Bs[(wc + nt * 16 + lr) * 72 + kk * 32 + lg * 8]);
#pragma unroll
      for (int mt = 0; mt < 4; ++mt)
#pragma unroll
        for (int nt = 0; nt < 4; ++nt)
          acc[mt][nt] = __builtin_amdgcn_mfma_f32_16x16x32_f16(af[mt], bf[nt], acc[mt][nt], 0, 0, 0);
    }
    __syncthreads();
  }
  const int p = n0 >> 9;   // block-uniform: 0=Q,1=K,2=V
  const float scl = (p == 0) ? 0.125f : (p == 1) ? 1.44269504f : 1.0f;
  if (p < 2) {
#pragma unroll
    for (int nt = 0; nt < 4; ++nt) {
      int n = n0 + wc + nt * 16 + lr;
      float bv = bias[n];
      int c = n & 511, h = c >> 6, d = c & 63;
#pragma unroll
      for (int mt = 0; mt < 4; ++mt)
#pragma unroll
        for (int r = 0; r < 4; ++r) {
          int m = m0 + wr + mt * 16 + lg * 4 + r;
          int bb = m >> 10, nn = m & 1023;
          qkv[p * 4194304 + ((bb * NH + h) * SEQ + nn) * DH + d] = (_Float16)((acc[mt][nt][r] + bv) * scl);
        }
    }
  } else {
#pragma unroll
    for (int nt = 0; nt < 4; ++nt) {
      int n = n0 + wc + nt * 16 + lr;
      float bv = bias[n];
      int c = n & 511, h = c >> 6, d = c & 63;
#pragma unroll
      for (int mt = 0; mt < 4; ++mt) {
        int m = m0 + wr + mt * 16 + lg * 4;
        int bb = m >> 10, nn = m & 1023;
        half4 st;
#pragma unroll
        for (int r = 0; r < 4; ++r) st[r] = (_Float16)(acc[mt][nt][r] + bv);
        *reinterpret_cast<half4*>(&qkv[8388608 + ((bb * NH + h) * DH + d) * SEQ + nn]) = st;
      }
    }
  }
}

// ---------------- fused attention: 1024 blocks x 4 waves, 16 q-rows/wave, LDS dbuf ----------------
__global__ __launch_bounds__(256, 4) void attn5(const _Float16* __restrict__ qkv,
                                                const float* __restrict__ mask,
                                                const unsigned char* __restrict__ ebins,
                                                const float* __restrict__ demb,
                                                const float* __restrict__ obias,
                                                _Float16* __restrict__ aout) {
  __shared__ __attribute__((aligned(16))) _Float16 KsBuf[2][64 * 72];
  __shared__ __attribute__((aligned(16))) _Float16 VtBuf[2][64 * 72];
  __shared__ float dembl[32];

  const int blk = blockIdx.x;                      // 1024 blocks
  const int lin = (blk & 7) * 128 + (blk >> 3);    // XCD-chunked: one batch b per XCD
  const int qt = lin & 15, h = (lin >> 4) & 7, b = lin >> 7;
  const int tid = threadIdx.x, w = tid >> 6, lane = tid & 63;
  const int lr = lane & 15, lg = lane >> 4;

  if (tid < 32) dembl[tid] = demb[tid * NH + h] * 1.44269504f;
  const float obh = 0.5f * obias[h] * 1.44269504f;
  const bool obh_nz = (obh != 0.f);

  const _Float16* Qg  = qkv + (size_t)(b * NH + h) * 65536;
  const _Float16* Kg  = qkv + 4194304 + (size_t)(b * NH + h) * 65536;
  const _Float16* Vtg = qkv + 8388608 + (size_t)(b * NH + h) * 65536;

  const int q_base = qt * 64 + w * 16;
  half8 qf[2];
#pragma unroll
  for (int ks = 0; ks < 2; ++ks)
    qf[ks] = *reinterpret_cast<const half8*>(&Qg[(q_base + lr) * DH + ks * 32 + lg * 8]);
  const float mq = mask[b * SEQ + q_base + lr];

  float m_run = -INFINITY, l_run = 0.f;
  f32x4 o[4] = {};

  const int sr = tid >> 2, sc = (tid & 3) * 16;
  // stage tile 0 into buf 0
  *reinterpret_cast<uint4*>(&KsBuf[0][sr * 72 + sc]) =
      *reinterpret_cast<const uint4*>(&Kg[sr * DH + sc]);
  *reinterpret_cast<uint4*>(&KsBuf[0][sr * 72 + sc + 8]) =
      *reinterpret_cast<const uint4*>(&Kg[sr * DH + sc + 8]);
  *reinterpret_cast<uint4*>(&VtBuf[0][sr * 72 + sc]) =
      *reinterpret_cast<const uint4*>(&Vtg[sr * SEQ + sc]);
  *reinterpret_cast<uint4*>(&VtBuf[0][sr * 72 + sc + 8]) =
      *reinterpret_cast<const uint4*>(&Vtg[sr * SEQ + sc + 8]);
  __syncthreads();

#pragma unroll 1
  for (int kt = 0; kt < 16; ++kt) {
    const int cur = kt & 1;
    // (a) issue next-tile global loads early (latency hides under compute)
    uint4 kA, kB, vA, vB;
    if (kt < 15) {
      const int kv = (kt + 1) * 64;
      kA = *reinterpret_cast<const uint4*>(&Kg[(kv + sr) * DH + sc]);
      kB = *reinterpret_cast<const uint4*>(&Kg[(kv + sr) * DH + sc + 8]);
      vA = *reinterpret_cast<const uint4*>(&Vtg[sr * SEQ + kv + sc]);
      vB = *reinterpret_cast<const uint4*>(&Vtg[sr * SEQ + kv + sc + 8]);
    }
    // (b) accumulator init: bias from 32-entry broadcast table + VALU sign/mask
    unsigned ebw[4];
#pragma unroll
    for (int ct = 0; ct < 4; ++ct)
      ebw[ct] = *reinterpret_cast<const unsigned*>(
          &ebins[(size_t)(b * SEQ + q_base + lr) * SEQ + kt * 64 + ct * 16 + lg * 4]);
    f32x4 s4t[4];
    if (obh_nz) {
#pragma unroll
      for (int ct = 0; ct < 4; ++ct)
#pragma unroll
        for (int r = 0; r < 4; ++r) {
          unsigned e = (ebw[ct] >> (8 * r)) & 255u;
          float bias = dembl[e & 31u] + ((e & 32u) ? obh : -obh);
          s4t[ct][r] = (e & 64u) ? -1.442695e9f : bias;
        }
    } else {
#pragma unroll
      for (int ct = 0; ct < 4; ++ct)
#pragma unroll
        for (int r = 0; r < 4; ++r) {
          unsigned e = (ebw[ct] >> (8 * r)) & 255u;
          float bias = dembl[e & 31u];
          s4t[ct][r] = (e & 64u) ? -1.442695e9f : bias;
        }
    }
    // QK^T swapped: S^T tile, row=k col=q
    __builtin_amdgcn_s_setprio(1);
#pragma unroll
    for (int ct = 0; ct < 4; ++ct) {
      half8 kf0 = *reinterpret_cast<const half8*>(&KsBuf[cur][(ct * 16 + lr) * 72 + lg * 8]);
      half8 kf1 = *reinterpret_cast<const half8*>(&KsBuf[cur][(ct * 16 + lr) * 72 + 32 + lg * 8]);
      s4t[ct] = __builtin_amdgcn_mfma_f32_16x16x32_f16(kf0, qf[0], s4t[ct], 0, 0, 0);
      s4t[ct] = __builtin_amdgcn_mfma_f32_16x16x32_f16(kf1, qf[1], s4t[ct], 0, 0, 0);
    }
    __builtin_amdgcn_s_setprio(0);
    // online softmax with defer-max (THR=8 in exp2 units); l kept lg-partial
    {
      float a0 = fmaxf(fmaxf(s4t[0][0], s4t[0][1]), fmaxf(s4t[0][2], s4t[0][3]));
      float a1 = fmaxf(fmaxf(s4t[1][0], s4t[1][1]), fmaxf(s4t[1][2], s4t[1][3]));
      float a2 = fmaxf(fmaxf(s4t[2][0], s4t[2][1]), fmaxf(s4t[2][2], s4t[2][3]));
      float a3 = fmaxf(fmaxf(s4t[3][0], s4t[3][1]), fmaxf(s4t[3][2], s4t[3][3]));
      float pm = fmaxf(fmaxf(a0, a1), fmaxf(a2, a3));
      pm = fmaxf(pm, __shfl_xor(pm, 16));
      pm = fmaxf(pm, __shfl_xor(pm, 32));
      if (__any((int)(pm > m_run + 8.0f))) {
        float newm = fmaxf(m_run, pm);
        float alpha = EXP2F(m_run - newm);
        m_run = newm; l_run *= alpha;
#pragma unroll
        for (int dt = 0; dt < 4; ++dt) o[dt] *= alpha;
      }
      float ss_ = 0.f;
#pragma unroll
      for (int ct = 0; ct < 4; ++ct)
#pragma unroll
        for (int r = 0; r < 4; ++r) {
          float pv = EXP2F(s4t[ct][r] - m_run);
          s4t[ct][r] = pv; ss_ += pv;
        }
      l_run += ss_;
    }
    // pack P to fp16 + in-register redistribution (lane bits (p2,p1)->(p3,p2))
    unsigned W[4][2];
#pragma unroll
    for (int ct = 0; ct < 4; ++ct) {
      W[ct][0] = pk2(s4t[ct][0], s4t[ct][1]);
      W[ct][1] = pk2(s4t[ct][2], s4t[ct][3]);
    }
    swap32(W[0][0], W[1][0]); swap32(W[0][1], W[1][1]);
    swap32(W[2][0], W[3][0]); swap32(W[2][1], W[3][1]);
    swap16(W[0][0], W[1][0]); swap16(W[0][1], W[1][1]);
    swap16(W[2][0], W[3][0]); swap16(W[2][1], W[3][1]);
    // (c) write next tile to other LDS buffer
    if (kt < 15) {
      *reinterpret_cast<uint4*>(&KsBuf[cur ^ 1][sr * 72 + sc]) = kA;
      *reinterpret_cast<uint4*>(&KsBuf[cur ^ 1][sr * 72 + sc + 8]) = kB;
      *reinterpret_cast<uint4*>(&VtBuf[cur ^ 1][sr * 72 + sc]) = vA;
      *reinterpret_cast<uint4*>(&VtBuf[cur ^ 1][sr * 72 + sc + 8]) = vB;
    }
    // (d) PV swapped: o^T[d][q] += Vt-frag x P-frag
    __builtin_amdgcn_s_setprio(1);
#pragma unroll
    for (int ks = 0; ks < 2; ++ks) {
      half8 pa = mk8(W[ks * 2][0], W[ks * 2][1], W[ks * 2 + 1][0], W[ks * 2 + 1][1]);
#pragma unroll
      for (int dt = 0; dt < 4; ++dt) {
        half8 vf = *reinterpret_cast<const half8*>(&VtBuf[cur][(dt * 16 + lr) * 72 + ks * 32 + lg * 8]);
        o[dt] = __builtin_amdgcn_mfma_f32_16x16x32_f16(vf, pa, o[dt], 0, 0, 0);
      }
    }
    __builtin_amdgcn_s_setprio(0);
    __syncthreads();
  }

  float s_ = l_run;
  s_ += __shfl_xor(s_, 16);
  s_ += __shfl_xor(s_, 32);
  const float linv = mq / s_;
#pragma unroll
  for (int dt = 0; dt < 4; ++dt) {
    half4 st;
#pragma unroll
    for (int r = 0; r < 4; ++r) st[r] = (_Float16)(o[dt][r] * linv);
    *reinterpret_cast<half4*>(
        &aout[(size_t)(b * SEQ + q_base + lr) * 512 + h * DH + dt * 16 + lg * 4]) = st;
  }
}

// ---------------- output projection GEMM (128x128 tile, BK=64) ----------------
__global__ __launch_bounds__(256) void out_gemm2(const _Float16* __restrict__ ah,
                                                 const _Float16* __restrict__ wh,
                                                 const float* __restrict__ ob,
                                                 float* __restrict__ out) {
  __shared__ __attribute__((aligned(16))) _Float16 As[128 * 72];
  __shared__ __attribute__((aligned(16))) _Float16 Bs[128 * 72];
  const int m0 = blockIdx.x * 128, n0 = blockIdx.y * 128;
  const int tid = threadIdx.x, w = tid >> 6, lane = tid & 63;
  const int lr = lane & 15, lg = lane >> 4;
  const int wr = (w >> 1) * 64, wc = (w & 1) * 64;
  f32x4 acc[4][4] = {};
  const int srow = tid >> 1, sseg = (tid & 1) * 32;
  for (int k0 = 0; k0 < 512; k0 += 64) {
#pragma unroll
    for (int s = 0; s < 4; ++s) {
      *reinterpret_cast<uint4*>(&As[srow * 72 + sseg + s * 8]) =
          *reinterpret_cast<const uint4*>(&ah[(m0 + srow) * 512 + k0 + sseg + s * 8]);
      *reinterpret_cast<uint4*>(&Bs[srow * 72 + sseg + s * 8]) =
          *reinterpret_cast<const uint4*>(&wh[(n0 + srow) * 512 + k0 + sseg + s * 8]);
    }
    __syncthreads();
#pragma unroll
    for (int kk = 0; kk < 2; ++kk) {
      half8 af[4], bf[4];
#pragma unroll
      for (int mt = 0; mt < 4; ++mt)
        af[mt] = *reinterpret_cast<const half8*>(&As[(wr + mt * 16 + lr) * 72 + kk * 32 + lg * 8]);
#pragma unroll
      for (int nt = 0; nt < 4; ++nt)
        bf[nt] = *reinterpret_cast<const half8*>(&Bs[(wc + nt * 16 + lr) * 72 + kk * 32 + lg * 8]);
#pragma unroll
      for (int mt = 0; mt < 4; ++mt)
#pragma unroll
        for (int nt = 0; nt < 4; ++nt)
          acc[mt][nt] = __builtin_amdgcn_mfma_f32_16x16x32_f16(af[mt], bf[nt], acc[mt][nt], 0, 0, 0);
    }
    __syncthreads();
  }
#pragma unroll
  for (int nt = 0; nt < 4; ++nt) {
    int n = n0 + wc + nt * 16 + lr;
    float bv = ob[n];
#pragma unroll
    for (int mt = 0; mt < 4; ++mt)
#pragma unroll
      for (int r = 0; r < 4; ++r) {
        int m = m0 + wr + mt * 16 + lg * 4 + r;
        out[m * 512 + n] = acc[mt][nt][r] + bv;
      }
  }
}

extern "C" void kernel_launch(void* const* d_in, const int* in_sizes, int n_in,
                              void* d_out, int out_size, void* d_ws, size_t ws_size,
                              hipStream_t stream) {
  const float* x         = (const float*)d_in[0];
  const int*   positions = (const int*)d_in[1];
  const float* mask      = (const float*)d_in[2];
  const float* qw        = (const float*)d_in[3];
  const float* qb        = (const float*)d_in[4];
  const float* kw        = (const float*)d_in[5];
  const float* kb        = (const float*)d_in[6];
  const float* vw        = (const float*)d_in[7];
  const float* vb        = (const float*)d_in[8];
  const float* ow        = (const float*)d_in[9];
  const float* ob        = (const float*)d_in[10];
  const float* demb      = (const float*)d_in[11];
  const float* obias     = (const float*)d_in[12];
  const float* edges     = (const float*)d_in[13];

  char* ws = (char*)d_ws;
  _Float16* xh        = (_Float16*)(ws);                  // [0, 8M) — dead after qkv_gemm2
  unsigned char* ebins = (unsigned char*)(ws);            // reuses xh region after qkv_gemm2
  _Float16* qkv       = (_Float16*)(ws + 8388608);        // Q*0.125 | K*log2e | V^T  (24 MB)
  _Float16* aouth     = (_Float16*)(ws + 33554432);       // 8 MB
  _Float16* wqkvh     = (_Float16*)(ws + 41943040);       // 1.5 MB
  _Float16* owh       = (_Float16*)(ws + 43515904);       // 0.5 MB
  float*    qkvbias   = (float*)(ws + 44040192);          // 6 KB
  unsigned char* lutd = (unsigned char*)(ws + 44046336);  // 5120 B
  float*    outp      = (float*)d_out;

  prep_all<<<5142, 256, 0, stream>>>(x, qw, kw, vw, ow, qb, kb, vb, edges,
                                     xh, wqkvh, owh, qkvbias, lutd);
  qkv_gemm2<<<dim3(64, 12), 256, 0, stream>>>(xh, wqkvh, qkvbias, qkv);
  prep_ebins<<<2048, 256, 0, stream>>>(positions, mask, lutd, ebins);  // overwrites xh region
  attn5<<<1024, 256, 0, stream>>>(qkv, mask, ebins, demb, obias, aouth);
  out_gemm2<<<dim3(64, 4), 256, 0, stream>>>(aouth, owh, ob, outp);
}